// Round 12
// baseline (49.411 us; speedup 1.0000x reference)
//
#include <hip/hip_runtime.h>
#include <hip/hip_bf16.h>
#include <math.h>

#define NHEADS 4
#define DKK 16
#define CC 64
#define BB 2
#define NN 4096
#define NBH 8
#define EPSF 1e-8f
#define KSPLIT 8
#define TPAIRS 16         // 32-key tile-pairs per wave (512 keys per split)
#define NFRAG 2           // q-fragments per wave (32 q-rows per block)
#define LOG2E 1.44269504088896340736f

typedef __attribute__((ext_vector_type(8))) short bf8;
typedef __attribute__((ext_vector_type(4))) float f4;

union Frag { bf8 v; struct { uint2 lo, hi; } p; uint4 q; };

__device__ __forceinline__ unsigned short f2bf(float f) {
    union { float f; unsigned int u; } v; v.f = f;
    unsigned int r = v.u + 0x7FFFu + ((v.u >> 16) & 1u);   // RNE
    return (unsigned short)(r >> 16);
}

// pack two f32 -> u32 of 2 bf16 (RNE, lo|hi<<16) -- NO inline asm: the
// compiler lowers this to v_cvt_pk_bf16_f32 itself (m240: hand-asm cvt_pk
// is both slower and, per R8/R10/R11 failures, a corruption suspect).
__device__ __forceinline__ unsigned int pk2bf(float lo, float hi) {
    union { __hip_bfloat162 h; unsigned int u; } cv;
    cv.h = __float22bfloat162_rn(make_float2(lo, hi));
    return cv.u;
}

// ---------------------------------------------------------------------------
// Stage 1: projections + normalize + bf16 convert, MFMA-ready layouts.
// QP/KP[bh][n][16] bf16 hi-only (Q scaled by log2e).
// VP hi-only, pair-interleaved: VP[bh][dv(16)][pt(128)][32],
//   slot = ((n>>2)&3)*8 + ((n>>4)&1)*4 + (n&3)  (even tile -> j0..3, odd -> j4..7)
// (unchanged from R9 -- proven)
// ---------------------------------------------------------------------------
__global__ __launch_bounds__(256) void proj_kernel(
    const float* __restrict__ x, const float* __restrict__ wq,
    const float* __restrict__ wk, const float* __restrict__ wv,
    unsigned short* __restrict__ QP, unsigned short* __restrict__ KP,
    unsigned short* __restrict__ VP)
{
    __shared__ float sW[3 * CC * DKK];
    const int bh = blockIdx.x >> 6;
    const int n0 = (blockIdx.x & 63) * 64;
    const int b  = bh >> 2;
    const int h  = bh & 3;

    const int hbase = h * CC * DKK;
    for (int i = threadIdx.x; i < CC * DKK; i += 256) {
        sW[i]                = wq[hbase + i] * 0.125f;
        sW[CC * DKK + i]     = wk[hbase + i] * 0.125f;
        sW[2 * CC * DKK + i] = wv[hbase + i] * 0.125f;
    }
    __syncthreads();

    const int lane = threadIdx.x & 63;
    const int wave = threadIdx.x >> 6;
    const int n  = n0 + wave * 16 + (lane & 15);
    const int cq = lane >> 4;                     // this lane's c-quarter

    float aq[DKK] = {}, ak[DKK] = {}, av[DKK] = {};
    const float* xb = x + (size_t)b * CC * NN + n;
    for (int cc = 0; cc < 16; ++cc) {
        const int c = cq * 16 + cc;
        const float xv = xb[(size_t)c * NN];
        const float4* q4 = (const float4*)(sW + c * DKK);
        const float4* k4 = (const float4*)(sW + CC * DKK + c * DKK);
        const float4* v4 = (const float4*)(sW + 2 * CC * DKK + c * DKK);
        #pragma unroll
        for (int j = 0; j < 4; ++j) {
            float4 a = q4[j];
            aq[4*j+0] += xv * a.x; aq[4*j+1] += xv * a.y;
            aq[4*j+2] += xv * a.z; aq[4*j+3] += xv * a.w;
            float4 bk = k4[j];
            ak[4*j+0] += xv * bk.x; ak[4*j+1] += xv * bk.y;
            ak[4*j+2] += xv * bk.z; ak[4*j+3] += xv * bk.w;
            float4 cv = v4[j];
            av[4*j+0] += xv * cv.x; av[4*j+1] += xv * cv.y;
            av[4*j+2] += xv * cv.z; av[4*j+3] += xv * cv.w;
        }
    }
    #pragma unroll
    for (int i = 0; i < DKK; ++i) {
        aq[i] += __shfl_xor(aq[i], 16); aq[i] += __shfl_xor(aq[i], 32);
        ak[i] += __shfl_xor(ak[i], 16); ak[i] += __shfl_xor(ak[i], 32);
        av[i] += __shfl_xor(av[i], 16); av[i] += __shfl_xor(av[i], 32);
    }

    float sq = 0.f, sk = 0.f;
    #pragma unroll
    for (int i = 0; i < DKK; ++i) { sq += aq[i]*aq[i]; sk += ak[i]*ak[i]; }
    const float rq = LOG2E / (sqrtf(sq) + EPSF);   // log2e folded into Q
    const float rk = 1.0f / (sqrtf(sk) + EPSF);

    if (cq == 0) {                                 // QP store (hi-only)
        __attribute__((aligned(16))) unsigned short qp[16];
        #pragma unroll
        for (int i = 0; i < DKK; ++i) qp[i] = f2bf(aq[i] * rq);
        const size_t base = ((size_t)bh * NN + n) * 16;
        ((uint4*)(QP + base))[0] = ((const uint4*)qp)[0];
        ((uint4*)(QP + base))[1] = ((const uint4*)qp)[1];
    } else if (cq == 1) {                          // KP store (hi-only)
        __attribute__((aligned(16))) unsigned short kp[16];
        #pragma unroll
        for (int i = 0; i < DKK; ++i) kp[i] = f2bf(ak[i] * rk);
        const size_t base = ((size_t)bh * NN + n) * 16;
        ((uint4*)(KP + base))[0] = ((const uint4*)kp)[0];
        ((uint4*)(KP + base))[1] = ((const uint4*)kp)[1];
    } else {
        // VP scatter (hi-only): cq==2 -> dv 0..7, cq==3 -> dv 8..15
        const int vslot = ((n >> 2) & 3) * 8 + ((n >> 4) & 1) * 4 + (n & 3);
        const int dv0 = (cq == 2) ? 0 : 8;
        #pragma unroll
        for (int i = 0; i < 8; ++i) {
            const int dv = dv0 + i;
            VP[(((size_t)bh * DKK + dv) * 128 + (n >> 5)) * 32 + vslot] = f2bf(av[dv]);
        }
    }
}

// ---------------------------------------------------------------------------
// One 32-key tile-pair x NFRAG q-frags: 4S+2PV MFMA, 16 exp2 (NFRAG=2).
// PV packs both 16-key tiles into one MFMA (A=[V_e|V_o], B=[P_e|P_o]);
// l accumulated on the VALU + post-loop shfl reduce. (R9-proven math;
// inline-asm cvt_pk replaced by intrinsic packing.)
// ---------------------------------------------------------------------------
__device__ __forceinline__ void attn_pair(
    const uint2 ke, const uint2 ko, const Frag& vc,
    const Frag* qh_, f4* oC, float* l_)
{
    const f4 zero = {0.f, 0.f, 0.f, 0.f};
    Frag kAe, kAo;
    kAe.p.lo = ke; kAe.p.hi = make_uint2(0u, 0u);
    kAo.p.lo = ko; kAo.p.hi = make_uint2(0u, 0u);

    #pragma unroll
    for (int f = 0; f < NFRAG; ++f) {
        f4 se = __builtin_amdgcn_mfma_f32_16x16x32_bf16(kAe.v, qh_[f].v, zero, 0, 0, 0);
        f4 so = __builtin_amdgcn_mfma_f32_16x16x32_bf16(kAo.v, qh_[f].v, zero, 0, 0, 0);

        const float pe0 = __builtin_amdgcn_exp2f(se[0]);
        const float pe1 = __builtin_amdgcn_exp2f(se[1]);
        const float pe2 = __builtin_amdgcn_exp2f(se[2]);
        const float pe3 = __builtin_amdgcn_exp2f(se[3]);
        const float po0 = __builtin_amdgcn_exp2f(so[0]);
        const float po1 = __builtin_amdgcn_exp2f(so[1]);
        const float po2 = __builtin_amdgcn_exp2f(so[2]);
        const float po3 = __builtin_amdgcn_exp2f(so[3]);

        l_[f] += ((pe0 + pe1) + (pe2 + pe3)) + ((po0 + po1) + (po2 + po3));

        Frag pB;
        pB.p.lo = make_uint2(pk2bf(pe0, pe1), pk2bf(pe2, pe3));  // even -> j0..3
        pB.p.hi = make_uint2(pk2bf(po0, po1), pk2bf(po2, po3));  // odd  -> j4..7

        oC[f] = __builtin_amdgcn_mfma_f32_16x16x32_bf16(vc.v, pB.v, oC[f], 0, 0, 0);
    }
}

// ---------------------------------------------------------------------------
// Stage 2 (fused): 1024 blocks x 8 waves. Block = (bh, 32 q-rows); wave = one
// key split (512 keys = 16 pairs) x 2 q-frags -> 8192 waves (2x R9's TLP).
// Per pair: 2x8B K + 1x16B V loads, 6 MFMA, 16 exp2. Prefetch depth 2 pairs,
// last two peeled (no OOB). R9-proven epilogue: LDS-reduce 8 splits,
// normalize, write O2T. bh = blockIdx&7 -> one bh's K/V per XCD L2.
// ---------------------------------------------------------------------------
__global__ __launch_bounds__(512, 4) void attn_kernel(
    const unsigned short* __restrict__ QP, const unsigned short* __restrict__ KP,
    const unsigned short* __restrict__ VP, float* __restrict__ O2T)
{
    const int bh    = blockIdx.x & 7;
    const int qg    = blockIdx.x >> 3;          // 0..127, 32 q-rows each
    const int split = threadIdx.x >> 6;         // 0..7
    const int lane  = threadIdx.x & 63;
    const int g = lane >> 4;
    const int r = lane & 15;

    // 2 Q frags (hi-only), each an 8B load duplicated into both B halves
    Frag qh_[NFRAG];
    #pragma unroll
    for (int f = 0; f < NFRAG; ++f) {
        const uint2 qv = *(const uint2*)(QP + ((size_t)bh * NN + qg * 32 + f * 16 + r) * 16 + g * 4);
        qh_[f].p.lo = qv; qh_[f].p.hi = qv;
    }

    const int key0 = split * (NN / KSPLIT);
    const unsigned short* kp_p = KP + ((size_t)bh * NN + key0 + r) * 16 + g * 4;
    const unsigned short* vp_p = VP + (((size_t)bh * DKK + r) * 128 + (key0 >> 5)) * 32 + g * 8;

    f4 oC[NFRAG] = {{0.f,0.f,0.f,0.f},{0.f,0.f,0.f,0.f}};
    float l_[NFRAG] = {0.f, 0.f};

    // prefetch depth 2 pairs (pairs 0 and 1), unroll-2 main loop
    uint2 ke0 = *(const uint2*)kp_p;
    uint2 ko0 = *(const uint2*)(kp_p + 256);
    Frag  v0; v0.q = *(const uint4*)vp_p;
    uint2 ke1 = *(const uint2*)(kp_p + 512);
    uint2 ko1 = *(const uint2*)(kp_p + 768);
    Frag  v1; v1.q = *(const uint4*)(vp_p + 32);
    kp_p += 1024; vp_p += 64;                   // -> pair t+2

    for (int t = 0; t < TPAIRS - 2; t += 2) {   // 7 iters; max prefetch pair 15
        const uint2 kne0 = *(const uint2*)kp_p;
        const uint2 kno0 = *(const uint2*)(kp_p + 256);
        Frag vn0; vn0.q = *(const uint4*)vp_p;
        attn_pair(ke0, ko0, v0, qh_, oC, l_);
        const uint2 kne1 = *(const uint2*)(kp_p + 512);
        const uint2 kno1 = *(const uint2*)(kp_p + 768);
        Frag vn1; vn1.q = *(const uint4*)(vp_p + 32);
        attn_pair(ke1, ko1, v1, qh_, oC, l_);
        ke0 = kne0; ko0 = kno0; v0 = vn0;
        ke1 = kne1; ko1 = kno1; v1 = vn1;
        kp_p += 1024; vp_p += 64;
    }
    attn_pair(ke0, ko0, v0, qh_, oC, l_);       // pair 14
    attn_pair(ke1, ko1, v1, qh_, oC, l_);       // pair 15

    // reduce the 4 lane-groups (stride-16 lanes) -> full split-l in every lane
    #pragma unroll
    for (int f = 0; f < NFRAG; ++f) {
        l_[f] += __shfl_xor(l_[f], 16);
        l_[f] += __shfl_xor(l_[f], 32);
    }

    // ---- cross-split reduction in LDS (R9-proven epilogue) ----
    __shared__ float sO[KSPLIT][NFRAG][DKK][17];    // ~17.4 KB, padded
    __shared__ float sL[KSPLIT][NFRAG][17];         // ~1.1 KB
    #pragma unroll
    for (int f = 0; f < NFRAG; ++f)
        #pragma unroll
        for (int i = 0; i < 4; ++i)
            sO[split][f][g * 4 + i][r] = oC[f][i];
    if (g == 0) {
        #pragma unroll
        for (int f = 0; f < NFRAG; ++f) sL[split][f][r] = l_[f];
    }
    __syncthreads();

    // 512 threads -> one output element each: qq = tid&31, dv = tid>>5
    const int qq = threadIdx.x & 31;
    const int f  = qq >> 4;
    const int rr = qq & 15;
    const int dv = threadIdx.x >> 5;            // 0..15
    const int b = bh >> 2, h = bh & 3;

    float den = 0.f;
    #pragma unroll
    for (int s = 0; s < KSPLIT; ++s) den += sL[s][f][rr];
    const float rd = 1.0f / den;

    float num = 0.f;
    #pragma unroll
    for (int s = 0; s < KSPLIT; ++s) num += sO[s][f][dv][rr];
    O2T[((size_t)b * CC + h * DKK + dv) * NN + qg * 32 + qq] = num * rd;
}

// ---------------------------------------------------------------------------
// Stage 3: y[b,c,n] = sum_{h,v} o[b,h,n,v] * wo[h,c,v] / 8.
// 4 c-outputs per thread; wo reads are block-uniform (scalar cache).
// (unchanged from R9 -- proven)
// ---------------------------------------------------------------------------
__global__ __launch_bounds__(256) void out_kernel(
    const float* __restrict__ O2T, const float* __restrict__ wo,
    float* __restrict__ y)
{
    const int idx = blockIdx.x * 256 + threadIdx.x;   // (b*16 + cg)*NN + n
    const int n   = idx & (NN - 1);
    const int bcg = idx >> 12;
    const int cg  = bcg & 15;                         // c-group of 4
    const int b   = bcg >> 4;

    const float* ob = O2T + (size_t)b * CC * NN + n;
    float acc[4] = {0.f, 0.f, 0.f, 0.f};
    #pragma unroll
    for (int h = 0; h < NHEADS; ++h)
        #pragma unroll
        for (int v = 0; v < DKK; ++v) {
            const float o = ob[(size_t)(h * DKK + v) * NN];
            #pragma unroll
            for (int c2 = 0; c2 < 4; ++c2)
                acc[c2] += o * wo[((size_t)h * CC + cg * 4 + c2) * DKK + v];
        }
    #pragma unroll
    for (int c2 = 0; c2 < 4; ++c2)
        y[((size_t)b * CC + cg * 4 + c2) * NN + n] = acc[c2] * 0.125f;
}

// ---------------------------------------------------------------------------
extern "C" void kernel_launch(void* const* d_in, const int* in_sizes, int n_in,
                              void* d_out, int out_size, void* d_ws, size_t ws_size,
                              hipStream_t stream)
{
    const float* x  = (const float*)d_in[0];
    const float* wq = (const float*)d_in[1];
    const float* wk = (const float*)d_in[2];
    const float* wv = (const float*)d_in[3];
    const float* wo = (const float*)d_in[4];
    float* y = (float*)d_out;

    const size_t QKE = (size_t)NBH * NN * 16;           // QP/KP: 512K shorts
    const size_t VE  = (size_t)NBH * DKK * 128 * 32;    // VP: 512K shorts
    unsigned short* QP = (unsigned short*)d_ws;
    unsigned short* KP = QP + QKE;
    unsigned short* VP = KP + QKE;
    float* O2T = (float*)(VP + VE);

    proj_kernel<<<NBH * 64, 256, 0, stream>>>(x, wq, wk, wv, QP, KP, VP);
    attn_kernel<<<NBH * 128, 512, 0, stream>>>(QP, KP, VP, O2T);
    out_kernel<<<(BB * 16 * NN) / 256, 256, 0, stream>>>(O2T, wo, y);
}

// Round 13
// 47.700 us; speedup vs baseline: 1.0359x; 1.0359x over previous
//
#include <hip/hip_runtime.h>
#include <hip/hip_bf16.h>
#include <math.h>

#define NHEADS 4
#define DKK 16
#define CC 64
#define BB 2
#define NN 4096
#define NBH 8
#define EPSF 1e-8f
#define KSPLIT 8
#define TPAIRS 16         // 32-key tile-pairs per wave (512 keys per split)
#define NFRAG 4           // q-fragments per wave (64 q-rows per block)
#define LOG2E 1.44269504088896340736f

typedef __attribute__((ext_vector_type(8))) short bf8;
typedef __attribute__((ext_vector_type(4))) float f4;

union Frag { bf8 v; struct { uint2 lo, hi; } p; uint4 q; };

__device__ __forceinline__ unsigned short f2bf(float f) {
    union { float f; unsigned int u; } v; v.f = f;
    unsigned int r = v.u + 0x7FFFu + ((v.u >> 16) & 1u);   // RNE
    return (unsigned short)(r >> 16);
}

// pack two f32 -> u32 of 2 bf16 (RNE, lo|hi<<16). Pure HIP intrinsic -- the
// compiler lowers to v_cvt_pk_bf16_f32. (R12 experiment: the hand-asm version
// of this was the R8/R10/R11 corruption source; intrinsic is proven clean.)
__device__ __forceinline__ unsigned int pk2bf(float lo, float hi) {
    union { __hip_bfloat162 h; unsigned int u; } cv;
    cv.h = __float22bfloat162_rn(make_float2(lo, hi));
    return cv.u;
}

// ---------------------------------------------------------------------------
// Stage 1: projections + normalize + bf16 convert, MFMA-ready layouts.
// QP/KP[bh][n][16] bf16 hi-only (Q scaled by log2e).
// VP hi-only, pair-interleaved: VP[bh][dv(16)][pt(128)][32],
//   slot = ((n>>2)&3)*8 + ((n>>4)&1)*4 + (n&3)  (even tile -> j0..3, odd -> j4..7)
// (unchanged from R9 -- proven)
// ---------------------------------------------------------------------------
__global__ __launch_bounds__(256) void proj_kernel(
    const float* __restrict__ x, const float* __restrict__ wq,
    const float* __restrict__ wk, const float* __restrict__ wv,
    unsigned short* __restrict__ QP, unsigned short* __restrict__ KP,
    unsigned short* __restrict__ VP)
{
    __shared__ float sW[3 * CC * DKK];
    const int bh = blockIdx.x >> 6;
    const int n0 = (blockIdx.x & 63) * 64;
    const int b  = bh >> 2;
    const int h  = bh & 3;

    const int hbase = h * CC * DKK;
    for (int i = threadIdx.x; i < CC * DKK; i += 256) {
        sW[i]                = wq[hbase + i] * 0.125f;
        sW[CC * DKK + i]     = wk[hbase + i] * 0.125f;
        sW[2 * CC * DKK + i] = wv[hbase + i] * 0.125f;
    }
    __syncthreads();

    const int lane = threadIdx.x & 63;
    const int wave = threadIdx.x >> 6;
    const int n  = n0 + wave * 16 + (lane & 15);
    const int cq = lane >> 4;                     // this lane's c-quarter

    float aq[DKK] = {}, ak[DKK] = {}, av[DKK] = {};
    const float* xb = x + (size_t)b * CC * NN + n;
    for (int cc = 0; cc < 16; ++cc) {
        const int c = cq * 16 + cc;
        const float xv = xb[(size_t)c * NN];
        const float4* q4 = (const float4*)(sW + c * DKK);
        const float4* k4 = (const float4*)(sW + CC * DKK + c * DKK);
        const float4* v4 = (const float4*)(sW + 2 * CC * DKK + c * DKK);
        #pragma unroll
        for (int j = 0; j < 4; ++j) {
            float4 a = q4[j];
            aq[4*j+0] += xv * a.x; aq[4*j+1] += xv * a.y;
            aq[4*j+2] += xv * a.z; aq[4*j+3] += xv * a.w;
            float4 bk = k4[j];
            ak[4*j+0] += xv * bk.x; ak[4*j+1] += xv * bk.y;
            ak[4*j+2] += xv * bk.z; ak[4*j+3] += xv * bk.w;
            float4 cv = v4[j];
            av[4*j+0] += xv * cv.x; av[4*j+1] += xv * cv.y;
            av[4*j+2] += xv * cv.z; av[4*j+3] += xv * cv.w;
        }
    }
    #pragma unroll
    for (int i = 0; i < DKK; ++i) {
        aq[i] += __shfl_xor(aq[i], 16); aq[i] += __shfl_xor(aq[i], 32);
        ak[i] += __shfl_xor(ak[i], 16); ak[i] += __shfl_xor(ak[i], 32);
        av[i] += __shfl_xor(av[i], 16); av[i] += __shfl_xor(av[i], 32);
    }

    float sq = 0.f, sk = 0.f;
    #pragma unroll
    for (int i = 0; i < DKK; ++i) { sq += aq[i]*aq[i]; sk += ak[i]*ak[i]; }
    const float rq = LOG2E / (sqrtf(sq) + EPSF);   // log2e folded into Q
    const float rk = 1.0f / (sqrtf(sk) + EPSF);

    if (cq == 0) {                                 // QP store (hi-only)
        __attribute__((aligned(16))) unsigned short qp[16];
        #pragma unroll
        for (int i = 0; i < DKK; ++i) qp[i] = f2bf(aq[i] * rq);
        const size_t base = ((size_t)bh * NN + n) * 16;
        ((uint4*)(QP + base))[0] = ((const uint4*)qp)[0];
        ((uint4*)(QP + base))[1] = ((const uint4*)qp)[1];
    } else if (cq == 1) {                          // KP store (hi-only)
        __attribute__((aligned(16))) unsigned short kp[16];
        #pragma unroll
        for (int i = 0; i < DKK; ++i) kp[i] = f2bf(ak[i] * rk);
        const size_t base = ((size_t)bh * NN + n) * 16;
        ((uint4*)(KP + base))[0] = ((const uint4*)kp)[0];
        ((uint4*)(KP + base))[1] = ((const uint4*)kp)[1];
    } else {
        // VP scatter (hi-only): cq==2 -> dv 0..7, cq==3 -> dv 8..15
        const int vslot = ((n >> 2) & 3) * 8 + ((n >> 4) & 1) * 4 + (n & 3);
        const int dv0 = (cq == 2) ? 0 : 8;
        #pragma unroll
        for (int i = 0; i < 8; ++i) {
            const int dv = dv0 + i;
            VP[(((size_t)bh * DKK + dv) * 128 + (n >> 5)) * 32 + vslot] = f2bf(av[dv]);
        }
    }
}

// ---------------------------------------------------------------------------
// One 32-key tile-pair x 4 q-frags: 12 MFMA (8 S + 4 PV), 32 exp2.
// PV packs both 16-key tiles into one MFMA (A=[V_e|V_o], B=[P_e|P_o]);
// l accumulated on the VALU + post-loop shfl reduce. (R9-proven structure;
// intrinsic pack per R12.)
// ---------------------------------------------------------------------------
__device__ __forceinline__ void attn_pair(
    const uint2 ke, const uint2 ko, const Frag& vc,
    const Frag* qh_, f4* oC, float* l_)
{
    const f4 zero = {0.f, 0.f, 0.f, 0.f};
    Frag kAe, kAo;
    kAe.p.lo = ke; kAe.p.hi = make_uint2(0u, 0u);
    kAo.p.lo = ko; kAo.p.hi = make_uint2(0u, 0u);

    #pragma unroll
    for (int f = 0; f < NFRAG; ++f) {
        f4 se = __builtin_amdgcn_mfma_f32_16x16x32_bf16(kAe.v, qh_[f].v, zero, 0, 0, 0);
        f4 so = __builtin_amdgcn_mfma_f32_16x16x32_bf16(kAo.v, qh_[f].v, zero, 0, 0, 0);

        const float pe0 = __builtin_amdgcn_exp2f(se[0]);
        const float pe1 = __builtin_amdgcn_exp2f(se[1]);
        const float pe2 = __builtin_amdgcn_exp2f(se[2]);
        const float pe3 = __builtin_amdgcn_exp2f(se[3]);
        const float po0 = __builtin_amdgcn_exp2f(so[0]);
        const float po1 = __builtin_amdgcn_exp2f(so[1]);
        const float po2 = __builtin_amdgcn_exp2f(so[2]);
        const float po3 = __builtin_amdgcn_exp2f(so[3]);

        l_[f] += ((pe0 + pe1) + (pe2 + pe3)) + ((po0 + po1) + (po2 + po3));

        Frag pB;
        pB.p.lo = make_uint2(pk2bf(pe0, pe1), pk2bf(pe2, pe3));  // even -> j0..3
        pB.p.hi = make_uint2(pk2bf(po0, po1), pk2bf(po2, po3));  // odd  -> j4..7

        oC[f] = __builtin_amdgcn_mfma_f32_16x16x32_bf16(vc.v, pB.v, oC[f], 0, 0, 0);
    }
}

// ---------------------------------------------------------------------------
// Stage 2 (fused): 512 blocks x 8 waves. Block = (bh, 64 q-rows); wave = one
// key split (512 keys = 16 pairs) x 4 q-frags (max per-load reuse -- the
// R12 experiment showed halving reuse for 2x TLP costs 7 us). Per pair:
// 2x8B K + 1x16B V loads, 12 MFMA, 32 exp2. Prefetch depth 2 pairs, last two
// peeled (no OOB -> replay-deterministic). Epilogue: LDS-reduce 8 splits,
// normalize, write O2T. bh = blockIdx&7 -> one bh's K/V per XCD L2.
// ---------------------------------------------------------------------------
__global__ __launch_bounds__(512, 4) void attn_kernel(
    const unsigned short* __restrict__ QP, const unsigned short* __restrict__ KP,
    const unsigned short* __restrict__ VP, float* __restrict__ O2T)
{
    const int bh    = blockIdx.x & 7;
    const int qg    = blockIdx.x >> 3;          // 0..63, 64 q-rows each
    const int split = threadIdx.x >> 6;         // 0..7
    const int lane  = threadIdx.x & 63;
    const int g = lane >> 4;
    const int r = lane & 15;

    // 4 Q frags (hi-only), each an 8B load duplicated into both B halves
    Frag qh_[NFRAG];
    #pragma unroll
    for (int f = 0; f < NFRAG; ++f) {
        const uint2 qv = *(const uint2*)(QP + ((size_t)bh * NN + qg * 64 + f * 16 + r) * 16 + g * 4);
        qh_[f].p.lo = qv; qh_[f].p.hi = qv;
    }

    const int key0 = split * (NN / KSPLIT);
    const unsigned short* kp_p = KP + ((size_t)bh * NN + key0 + r) * 16 + g * 4;
    const unsigned short* vp_p = VP + (((size_t)bh * DKK + r) * 128 + (key0 >> 5)) * 32 + g * 8;

    f4 oC[NFRAG] = {{0.f,0.f,0.f,0.f},{0.f,0.f,0.f,0.f},{0.f,0.f,0.f,0.f},{0.f,0.f,0.f,0.f}};
    float l_[NFRAG] = {0.f, 0.f, 0.f, 0.f};

    // prefetch depth 2 pairs (pairs 0 and 1), unroll-2 main loop
    uint2 ke0 = *(const uint2*)kp_p;
    uint2 ko0 = *(const uint2*)(kp_p + 256);
    Frag  v0; v0.q = *(const uint4*)vp_p;
    uint2 ke1 = *(const uint2*)(kp_p + 512);
    uint2 ko1 = *(const uint2*)(kp_p + 768);
    Frag  v1; v1.q = *(const uint4*)(vp_p + 32);
    kp_p += 1024; vp_p += 64;                   // -> pair t+2

    for (int t = 0; t < TPAIRS - 2; t += 2) {   // 7 iters; max prefetch pair 15
        const uint2 kne0 = *(const uint2*)kp_p;
        const uint2 kno0 = *(const uint2*)(kp_p + 256);
        Frag vn0; vn0.q = *(const uint4*)vp_p;
        attn_pair(ke0, ko0, v0, qh_, oC, l_);
        const uint2 kne1 = *(const uint2*)(kp_p + 512);
        const uint2 kno1 = *(const uint2*)(kp_p + 768);
        Frag vn1; vn1.q = *(const uint4*)(vp_p + 32);
        attn_pair(ke1, ko1, v1, qh_, oC, l_);
        ke0 = kne0; ko0 = kno0; v0 = vn0;
        ke1 = kne1; ko1 = kno1; v1 = vn1;
        kp_p += 1024; vp_p += 64;
    }
    attn_pair(ke0, ko0, v0, qh_, oC, l_);       // pair 14
    attn_pair(ke1, ko1, v1, qh_, oC, l_);       // pair 15

    // reduce the 4 lane-groups (stride-16 lanes) -> full split-l in every lane
    #pragma unroll
    for (int f = 0; f < NFRAG; ++f) {
        l_[f] += __shfl_xor(l_[f], 16);
        l_[f] += __shfl_xor(l_[f], 32);
    }

    // ---- cross-split reduction in LDS (R9-proven epilogue) ----
    __shared__ float sO[KSPLIT][NFRAG][DKK][17];    // ~34.8 KB, padded
    __shared__ float sL[KSPLIT][NFRAG][17];         // ~2.2 KB
    #pragma unroll
    for (int f = 0; f < NFRAG; ++f)
        #pragma unroll
        for (int i = 0; i < 4; ++i)
            sO[split][f][g * 4 + i][r] = oC[f][i];
    if (g == 0) {
        #pragma unroll
        for (int f = 0; f < NFRAG; ++f) sL[split][f][r] = l_[f];
    }
    __syncthreads();

    // 512 threads: each handles (qq, dv0) and (qq, dv0+8)
    const int qq  = threadIdx.x & 63;
    const int f   = qq >> 4;
    const int rr  = qq & 15;
    const int dv0 = threadIdx.x >> 6;           // 0..7
    const int b = bh >> 2, h = bh & 3;

    float den = 0.f;
    #pragma unroll
    for (int s = 0; s < KSPLIT; ++s) den += sL[s][f][rr];
    const float rd = 1.0f / den;

    #pragma unroll
    for (int dd = 0; dd < 2; ++dd) {
        const int dv = dv0 + dd * 8;
        float num = 0.f;
        #pragma unroll
        for (int s = 0; s < KSPLIT; ++s) num += sO[s][f][dv][rr];
        O2T[((size_t)b * CC + h * DKK + dv) * NN + qg * 64 + qq] = num * rd;
    }
}

// ---------------------------------------------------------------------------
// Stage 3: y[b,c,n] = sum_{h,v} o[b,h,n,v] * wo[h,c,v] / 8.
// 4 c-outputs per thread; wo reads are block-uniform (scalar cache).
// (unchanged from R9 -- proven)
// ---------------------------------------------------------------------------
__global__ __launch_bounds__(256) void out_kernel(
    const float* __restrict__ O2T, const float* __restrict__ wo,
    float* __restrict__ y)
{
    const int idx = blockIdx.x * 256 + threadIdx.x;   // (b*16 + cg)*NN + n
    const int n   = idx & (NN - 1);
    const int bcg = idx >> 12;
    const int cg  = bcg & 15;                         // c-group of 4
    const int b   = bcg >> 4;

    const float* ob = O2T + (size_t)b * CC * NN + n;
    float acc[4] = {0.f, 0.f, 0.f, 0.f};
    #pragma unroll
    for (int h = 0; h < NHEADS; ++h)
        #pragma unroll
        for (int v = 0; v < DKK; ++v) {
            const float o = ob[(size_t)(h * DKK + v) * NN];
            #pragma unroll
            for (int c2 = 0; c2 < 4; ++c2)
                acc[c2] += o * wo[((size_t)h * CC + cg * 4 + c2) * DKK + v];
        }
    #pragma unroll
    for (int c2 = 0; c2 < 4; ++c2)
        y[((size_t)b * CC + cg * 4 + c2) * NN + n] = acc[c2] * 0.125f;
}

// ---------------------------------------------------------------------------
extern "C" void kernel_launch(void* const* d_in, const int* in_sizes, int n_in,
                              void* d_out, int out_size, void* d_ws, size_t ws_size,
                              hipStream_t stream)
{
    const float* x  = (const float*)d_in[0];
    const float* wq = (const float*)d_in[1];
    const float* wk = (const float*)d_in[2];
    const float* wv = (const float*)d_in[3];
    const float* wo = (const float*)d_in[4];
    float* y = (float*)d_out;

    const size_t QKE = (size_t)NBH * NN * 16;           // QP/KP: 512K shorts
    const size_t VE  = (size_t)NBH * DKK * 128 * 32;    // VP: 512K shorts
    unsigned short* QP = (unsigned short*)d_ws;
    unsigned short* KP = QP + QKE;
    unsigned short* VP = KP + QKE;
    float* O2T = (float*)(VP + VE);

    proj_kernel<<<NBH * 64, 256, 0, stream>>>(x, wq, wk, wv, QP, KP, VP);
    attn_kernel<<<NBH * 64, 512, 0, stream>>>(QP, KP, VP, O2T);
    out_kernel<<<(BB * 16 * NN) / 256, 256, 0, stream>>>(O2T, wo, y);
}

// Round 14
// 45.813 us; speedup vs baseline: 1.0785x; 1.0412x over previous
//
#include <hip/hip_runtime.h>
#include <hip/hip_bf16.h>
#include <math.h>

#define NHEADS 4
#define DKK 16
#define CC 64
#define BB 2
#define NN 4096
#define NBH 8
#define EPSF 1e-8f
#define KSPLIT 8
#define TPAIRS 16         // 32-key tile-pairs per wave (512 keys per split)
#define NFRAG 4           // q-fragments per wave (64 q-rows per block)
#define LOG2E 1.44269504088896340736f

typedef __attribute__((ext_vector_type(8))) short bf8;
typedef __attribute__((ext_vector_type(4))) float f4;

union Frag { bf8 v; struct { uint2 lo, hi; } p; uint4 q; };

__device__ __forceinline__ unsigned short f2bf(float f) {
    union { float f; unsigned int u; } v; v.f = f;
    unsigned int r = v.u + 0x7FFFu + ((v.u >> 16) & 1u);   // RNE
    return (unsigned short)(r >> 16);
}

// pack two f32 -> u32 of 2 bf16, NO inline asm (asm cvt_pk caused the
// R8/R10/R11 regalloc corruption) and NO software-RNE (the hip_bf16
// intrinsic cost +5.4us in R13). Round-half-up (+0x8000, == RNE except at
// exact half-ulp ties) then one v_perm_b32 selects the two high halves:
//   perm(S0=hi, S1=lo, sel): codes 0-3 -> S1 bytes, 4-7 -> S0 bytes;
//   D = [lo.b2, lo.b3, hi.b2, hi.b3] -> sel 0x07060302.
// Valid for p > 0 (always: p = exp2(s), s in [-1.45, 1.45]).
__device__ __forceinline__ unsigned int pk2bf(float lo, float hi) {
    union { float f; unsigned int u; } a, b;
    a.f = lo; b.f = hi;
    return __builtin_amdgcn_perm(b.u + 0x8000u, a.u + 0x8000u, 0x07060302u);
}

// ---------------------------------------------------------------------------
// Stage 1: projections + normalize + bf16 convert, MFMA-ready layouts.
// QP/KP[bh][n][16] bf16 hi-only (Q scaled by log2e).
// VP hi-only, pair-interleaved: VP[bh][dv(16)][pt(128)][32],
//   slot = ((n>>2)&3)*8 + ((n>>4)&1)*4 + (n&3)  (even tile -> j0..3, odd -> j4..7)
// (unchanged from R9 -- proven)
// ---------------------------------------------------------------------------
__global__ __launch_bounds__(256) void proj_kernel(
    const float* __restrict__ x, const float* __restrict__ wq,
    const float* __restrict__ wk, const float* __restrict__ wv,
    unsigned short* __restrict__ QP, unsigned short* __restrict__ KP,
    unsigned short* __restrict__ VP)
{
    __shared__ float sW[3 * CC * DKK];
    const int bh = blockIdx.x >> 6;
    const int n0 = (blockIdx.x & 63) * 64;
    const int b  = bh >> 2;
    const int h  = bh & 3;

    const int hbase = h * CC * DKK;
    for (int i = threadIdx.x; i < CC * DKK; i += 256) {
        sW[i]                = wq[hbase + i] * 0.125f;
        sW[CC * DKK + i]     = wk[hbase + i] * 0.125f;
        sW[2 * CC * DKK + i] = wv[hbase + i] * 0.125f;
    }
    __syncthreads();

    const int lane = threadIdx.x & 63;
    const int wave = threadIdx.x >> 6;
    const int n  = n0 + wave * 16 + (lane & 15);
    const int cq = lane >> 4;                     // this lane's c-quarter

    float aq[DKK] = {}, ak[DKK] = {}, av[DKK] = {};
    const float* xb = x + (size_t)b * CC * NN + n;
    for (int cc = 0; cc < 16; ++cc) {
        const int c = cq * 16 + cc;
        const float xv = xb[(size_t)c * NN];
        const float4* q4 = (const float4*)(sW + c * DKK);
        const float4* k4 = (const float4*)(sW + CC * DKK + c * DKK);
        const float4* v4 = (const float4*)(sW + 2 * CC * DKK + c * DKK);
        #pragma unroll
        for (int j = 0; j < 4; ++j) {
            float4 a = q4[j];
            aq[4*j+0] += xv * a.x; aq[4*j+1] += xv * a.y;
            aq[4*j+2] += xv * a.z; aq[4*j+3] += xv * a.w;
            float4 bk = k4[j];
            ak[4*j+0] += xv * bk.x; ak[4*j+1] += xv * bk.y;
            ak[4*j+2] += xv * bk.z; ak[4*j+3] += xv * bk.w;
            float4 cv = v4[j];
            av[4*j+0] += xv * cv.x; av[4*j+1] += xv * cv.y;
            av[4*j+2] += xv * cv.z; av[4*j+3] += xv * cv.w;
        }
    }
    #pragma unroll
    for (int i = 0; i < DKK; ++i) {
        aq[i] += __shfl_xor(aq[i], 16); aq[i] += __shfl_xor(aq[i], 32);
        ak[i] += __shfl_xor(ak[i], 16); ak[i] += __shfl_xor(ak[i], 32);
        av[i] += __shfl_xor(av[i], 16); av[i] += __shfl_xor(av[i], 32);
    }

    float sq = 0.f, sk = 0.f;
    #pragma unroll
    for (int i = 0; i < DKK; ++i) { sq += aq[i]*aq[i]; sk += ak[i]*ak[i]; }
    const float rq = LOG2E / (sqrtf(sq) + EPSF);   // log2e folded into Q
    const float rk = 1.0f / (sqrtf(sk) + EPSF);

    if (cq == 0) {                                 // QP store (hi-only)
        __attribute__((aligned(16))) unsigned short qp[16];
        #pragma unroll
        for (int i = 0; i < DKK; ++i) qp[i] = f2bf(aq[i] * rq);
        const size_t base = ((size_t)bh * NN + n) * 16;
        ((uint4*)(QP + base))[0] = ((const uint4*)qp)[0];
        ((uint4*)(QP + base))[1] = ((const uint4*)qp)[1];
    } else if (cq == 1) {                          // KP store (hi-only)
        __attribute__((aligned(16))) unsigned short kp[16];
        #pragma unroll
        for (int i = 0; i < DKK; ++i) kp[i] = f2bf(ak[i] * rk);
        const size_t base = ((size_t)bh * NN + n) * 16;
        ((uint4*)(KP + base))[0] = ((const uint4*)kp)[0];
        ((uint4*)(KP + base))[1] = ((const uint4*)kp)[1];
    } else {
        // VP scatter (hi-only): cq==2 -> dv 0..7, cq==3 -> dv 8..15
        const int vslot = ((n >> 2) & 3) * 8 + ((n >> 4) & 1) * 4 + (n & 3);
        const int dv0 = (cq == 2) ? 0 : 8;
        #pragma unroll
        for (int i = 0; i < 8; ++i) {
            const int dv = dv0 + i;
            VP[(((size_t)bh * DKK + dv) * 128 + (n >> 5)) * 32 + vslot] = f2bf(av[dv]);
        }
    }
}

// ---------------------------------------------------------------------------
// One 32-key tile-pair x 4 q-frags: 12 MFMA (8 S + 4 PV), 32 exp2.
// PV packs both 16-key tiles into one MFMA (A=[V_e|V_o], B=[P_e|P_o]);
// l accumulated on the VALU + post-loop shfl reduce. (R9-proven structure;
// perm-based pack.)
// ---------------------------------------------------------------------------
__device__ __forceinline__ void attn_pair(
    const uint2 ke, const uint2 ko, const Frag& vc,
    const Frag* qh_, f4* oC, float* l_)
{
    const f4 zero = {0.f, 0.f, 0.f, 0.f};
    Frag kAe, kAo;
    kAe.p.lo = ke; kAe.p.hi = make_uint2(0u, 0u);
    kAo.p.lo = ko; kAo.p.hi = make_uint2(0u, 0u);

    #pragma unroll
    for (int f = 0; f < NFRAG; ++f) {
        f4 se = __builtin_amdgcn_mfma_f32_16x16x32_bf16(kAe.v, qh_[f].v, zero, 0, 0, 0);
        f4 so = __builtin_amdgcn_mfma_f32_16x16x32_bf16(kAo.v, qh_[f].v, zero, 0, 0, 0);

        const float pe0 = __builtin_amdgcn_exp2f(se[0]);
        const float pe1 = __builtin_amdgcn_exp2f(se[1]);
        const float pe2 = __builtin_amdgcn_exp2f(se[2]);
        const float pe3 = __builtin_amdgcn_exp2f(se[3]);
        const float po0 = __builtin_amdgcn_exp2f(so[0]);
        const float po1 = __builtin_amdgcn_exp2f(so[1]);
        const float po2 = __builtin_amdgcn_exp2f(so[2]);
        const float po3 = __builtin_amdgcn_exp2f(so[3]);

        l_[f] += ((pe0 + pe1) + (pe2 + pe3)) + ((po0 + po1) + (po2 + po3));

        Frag pB;
        pB.p.lo = make_uint2(pk2bf(pe0, pe1), pk2bf(pe2, pe3));  // even -> j0..3
        pB.p.hi = make_uint2(pk2bf(po0, po1), pk2bf(po2, po3));  // odd  -> j4..7

        oC[f] = __builtin_amdgcn_mfma_f32_16x16x32_bf16(vc.v, pB.v, oC[f], 0, 0, 0);
    }
}

// ---------------------------------------------------------------------------
// Stage 2 (fused): 512 blocks x 8 waves. Block = (bh, 64 q-rows); wave = one
// key split (512 keys = 16 pairs) x 4 q-frags (max per-load reuse -- R12
// showed halving reuse for 2x TLP costs 7 us). Per pair: 2x8B K + 1x16B V
// loads, 12 MFMA, 32 exp2. Prefetch depth 2 pairs, last two peeled (no OOB
// -> replay-deterministic). Epilogue: LDS-reduce 8 splits, normalize, write
// O2T. bh = blockIdx&7 -> one bh's K/V per XCD L2.
// ---------------------------------------------------------------------------
__global__ __launch_bounds__(512, 4) void attn_kernel(
    const unsigned short* __restrict__ QP, const unsigned short* __restrict__ KP,
    const unsigned short* __restrict__ VP, float* __restrict__ O2T)
{
    const int bh    = blockIdx.x & 7;
    const int qg    = blockIdx.x >> 3;          // 0..63, 64 q-rows each
    const int split = threadIdx.x >> 6;         // 0..7
    const int lane  = threadIdx.x & 63;
    const int g = lane >> 4;
    const int r = lane & 15;

    // 4 Q frags (hi-only), each an 8B load duplicated into both B halves
    Frag qh_[NFRAG];
    #pragma unroll
    for (int f = 0; f < NFRAG; ++f) {
        const uint2 qv = *(const uint2*)(QP + ((size_t)bh * NN + qg * 64 + f * 16 + r) * 16 + g * 4);
        qh_[f].p.lo = qv; qh_[f].p.hi = qv;
    }

    const int key0 = split * (NN / KSPLIT);
    const unsigned short* kp_p = KP + ((size_t)bh * NN + key0 + r) * 16 + g * 4;
    const unsigned short* vp_p = VP + (((size_t)bh * DKK + r) * 128 + (key0 >> 5)) * 32 + g * 8;

    f4 oC[NFRAG] = {{0.f,0.f,0.f,0.f},{0.f,0.f,0.f,0.f},{0.f,0.f,0.f,0.f},{0.f,0.f,0.f,0.f}};
    float l_[NFRAG] = {0.f, 0.f, 0.f, 0.f};

    // prefetch depth 2 pairs (pairs 0 and 1), unroll-2 main loop
    uint2 ke0 = *(const uint2*)kp_p;
    uint2 ko0 = *(const uint2*)(kp_p + 256);
    Frag  v0; v0.q = *(const uint4*)vp_p;
    uint2 ke1 = *(const uint2*)(kp_p + 512);
    uint2 ko1 = *(const uint2*)(kp_p + 768);
    Frag  v1; v1.q = *(const uint4*)(vp_p + 32);
    kp_p += 1024; vp_p += 64;                   // -> pair t+2

    for (int t = 0; t < TPAIRS - 2; t += 2) {   // 7 iters; max prefetch pair 15
        const uint2 kne0 = *(const uint2*)kp_p;
        const uint2 kno0 = *(const uint2*)(kp_p + 256);
        Frag vn0; vn0.q = *(const uint4*)vp_p;
        attn_pair(ke0, ko0, v0, qh_, oC, l_);
        const uint2 kne1 = *(const uint2*)(kp_p + 512);
        const uint2 kno1 = *(const uint2*)(kp_p + 768);
        Frag vn1; vn1.q = *(const uint4*)(vp_p + 32);
        attn_pair(ke1, ko1, v1, qh_, oC, l_);
        ke0 = kne0; ko0 = kno0; v0 = vn0;
        ke1 = kne1; ko1 = kno1; v1 = vn1;
        kp_p += 1024; vp_p += 64;
    }
    attn_pair(ke0, ko0, v0, qh_, oC, l_);       // pair 14
    attn_pair(ke1, ko1, v1, qh_, oC, l_);       // pair 15

    // reduce the 4 lane-groups (stride-16 lanes) -> full split-l in every lane
    #pragma unroll
    for (int f = 0; f < NFRAG; ++f) {
        l_[f] += __shfl_xor(l_[f], 16);
        l_[f] += __shfl_xor(l_[f], 32);
    }

    // ---- cross-split reduction in LDS (R9-proven epilogue) ----
    __shared__ float sO[KSPLIT][NFRAG][DKK][17];    // ~34.8 KB, padded
    __shared__ float sL[KSPLIT][NFRAG][17];         // ~2.2 KB
    #pragma unroll
    for (int f = 0; f < NFRAG; ++f)
        #pragma unroll
        for (int i = 0; i < 4; ++i)
            sO[split][f][g * 4 + i][r] = oC[f][i];
    if (g == 0) {
        #pragma unroll
        for (int f = 0; f < NFRAG; ++f) sL[split][f][r] = l_[f];
    }
    __syncthreads();

    // 512 threads: each handles (qq, dv0) and (qq, dv0+8)
    const int qq  = threadIdx.x & 63;
    const int f   = qq >> 4;
    const int rr  = qq & 15;
    const int dv0 = threadIdx.x >> 6;           // 0..7
    const int b = bh >> 2, h = bh & 3;

    float den = 0.f;
    #pragma unroll
    for (int s = 0; s < KSPLIT; ++s) den += sL[s][f][rr];
    const float rd = 1.0f / den;

    #pragma unroll
    for (int dd = 0; dd < 2; ++dd) {
        const int dv = dv0 + dd * 8;
        float num = 0.f;
        #pragma unroll
        for (int s = 0; s < KSPLIT; ++s) num += sO[s][f][dv][rr];
        O2T[((size_t)b * CC + h * DKK + dv) * NN + qg * 64 + qq] = num * rd;
    }
}

// ---------------------------------------------------------------------------
// Stage 3: y[b,c,n] = sum_{h,v} o[b,h,n,v] * wo[h,c,v] / 8.
// 4 c-outputs per thread; wo reads are block-uniform (scalar cache).
// (unchanged from R9 -- proven)
// ---------------------------------------------------------------------------
__global__ __launch_bounds__(256) void out_kernel(
    const float* __restrict__ O2T, const float* __restrict__ wo,
    float* __restrict__ y)
{
    const int idx = blockIdx.x * 256 + threadIdx.x;   // (b*16 + cg)*NN + n
    const int n   = idx & (NN - 1);
    const int bcg = idx >> 12;
    const int cg  = bcg & 15;                         // c-group of 4
    const int b   = bcg >> 4;

    const float* ob = O2T + (size_t)b * CC * NN + n;
    float acc[4] = {0.f, 0.f, 0.f, 0.f};
    #pragma unroll
    for (int h = 0; h < NHEADS; ++h)
        #pragma unroll
        for (int v = 0; v < DKK; ++v) {
            const float o = ob[(size_t)(h * DKK + v) * NN];
            #pragma unroll
            for (int c2 = 0; c2 < 4; ++c2)
                acc[c2] += o * wo[((size_t)h * CC + cg * 4 + c2) * DKK + v];
        }
    #pragma unroll
    for (int c2 = 0; c2 < 4; ++c2)
        y[((size_t)b * CC + cg * 4 + c2) * NN + n] = acc[c2] * 0.125f;
}

// ---------------------------------------------------------------------------
extern "C" void kernel_launch(void* const* d_in, const int* in_sizes, int n_in,
                              void* d_out, int out_size, void* d_ws, size_t ws_size,
                              hipStream_t stream)
{
    const float* x  = (const float*)d_in[0];
    const float* wq = (const float*)d_in[1];
    const float* wk = (const float*)d_in[2];
    const float* wv = (const float*)d_in[3];
    const float* wo = (const float*)d_in[4];
    float* y = (float*)d_out;

    const size_t QKE = (size_t)NBH * NN * 16;           // QP/KP: 512K shorts
    const size_t VE  = (size_t)NBH * DKK * 128 * 32;    // VP: 512K shorts
    unsigned short* QP = (unsigned short*)d_ws;
    unsigned short* KP = QP + QKE;
    unsigned short* VP = KP + QKE;
    float* O2T = (float*)(VP + VE);

    proj_kernel<<<NBH * 64, 256, 0, stream>>>(x, wq, wk, wv, QP, KP, VP);
    attn_kernel<<<NBH * 64, 512, 0, stream>>>(QP, KP, VP, O2T);
    out_kernel<<<(BB * 16 * NN) / 256, 256, 0, stream>>>(O2T, wo, y);
}

// Round 15
// 42.491 us; speedup vs baseline: 1.1629x; 1.0782x over previous
//
#include <hip/hip_runtime.h>
#include <math.h>

#define NHEADS 4
#define DKK 16
#define CC 64
#define BB 2
#define NN 4096
#define NBH 8
#define EPSF 1e-8f
#define KSPLIT 8
#define TPAIRS 16         // 32-key tile-pairs per wave (512 keys per split)
#define LOG2E 1.44269504088896340736f

typedef __attribute__((ext_vector_type(8))) short bf8;
typedef __attribute__((ext_vector_type(4))) float f4;

union Frag { bf8 v; struct { uint2 lo, hi; } p; uint4 q; };

__device__ __forceinline__ unsigned short f2bf(float f) {
    union { float f; unsigned int u; } v; v.f = f;
    unsigned int r = v.u + 0x7FFFu + ((v.u >> 16) & 1u);   // RNE
    return (unsigned short)(r >> 16);
}

// ---------------------------------------------------------------------------
// Stage 1: projections + normalize + bf16 convert, MFMA-ready layouts.
// QP/KP[bh][n][16] bf16 hi-only (Q scaled by log2e).
// VP hi-only, pair-interleaved: VP[bh][dv(16)][pt(128)][32],
//   slot = ((n>>2)&3)*8 + ((n>>4)&1)*4 + (n&3)  (even tile -> j0..3, odd -> j4..7)
// c-reduction split 4 ways across lane groups, combined via __shfl_xor.
// ---------------------------------------------------------------------------
__global__ __launch_bounds__(256) void proj_kernel(
    const float* __restrict__ x, const float* __restrict__ wq,
    const float* __restrict__ wk, const float* __restrict__ wv,
    unsigned short* __restrict__ QP, unsigned short* __restrict__ KP,
    unsigned short* __restrict__ VP)
{
    __shared__ float sW[3 * CC * DKK];
    const int bh = blockIdx.x >> 6;
    const int n0 = (blockIdx.x & 63) * 64;
    const int b  = bh >> 2;
    const int h  = bh & 3;

    const int hbase = h * CC * DKK;
    for (int i = threadIdx.x; i < CC * DKK; i += 256) {
        sW[i]                = wq[hbase + i] * 0.125f;
        sW[CC * DKK + i]     = wk[hbase + i] * 0.125f;
        sW[2 * CC * DKK + i] = wv[hbase + i] * 0.125f;
    }
    __syncthreads();

    const int lane = threadIdx.x & 63;
    const int wave = threadIdx.x >> 6;
    const int n  = n0 + wave * 16 + (lane & 15);
    const int cq = lane >> 4;                     // this lane's c-quarter

    float aq[DKK] = {}, ak[DKK] = {}, av[DKK] = {};
    const float* xb = x + (size_t)b * CC * NN + n;
    for (int cc = 0; cc < 16; ++cc) {
        const int c = cq * 16 + cc;
        const float xv = xb[(size_t)c * NN];
        const float4* q4 = (const float4*)(sW + c * DKK);
        const float4* k4 = (const float4*)(sW + CC * DKK + c * DKK);
        const float4* v4 = (const float4*)(sW + 2 * CC * DKK + c * DKK);
        #pragma unroll
        for (int j = 0; j < 4; ++j) {
            float4 a = q4[j];
            aq[4*j+0] += xv * a.x; aq[4*j+1] += xv * a.y;
            aq[4*j+2] += xv * a.z; aq[4*j+3] += xv * a.w;
            float4 bk = k4[j];
            ak[4*j+0] += xv * bk.x; ak[4*j+1] += xv * bk.y;
            ak[4*j+2] += xv * bk.z; ak[4*j+3] += xv * bk.w;
            float4 cv = v4[j];
            av[4*j+0] += xv * cv.x; av[4*j+1] += xv * cv.y;
            av[4*j+2] += xv * cv.z; av[4*j+3] += xv * cv.w;
        }
    }
    #pragma unroll
    for (int i = 0; i < DKK; ++i) {
        aq[i] += __shfl_xor(aq[i], 16); aq[i] += __shfl_xor(aq[i], 32);
        ak[i] += __shfl_xor(ak[i], 16); ak[i] += __shfl_xor(ak[i], 32);
        av[i] += __shfl_xor(av[i], 16); av[i] += __shfl_xor(av[i], 32);
    }

    float sq = 0.f, sk = 0.f;
    #pragma unroll
    for (int i = 0; i < DKK; ++i) { sq += aq[i]*aq[i]; sk += ak[i]*ak[i]; }
    const float rq = LOG2E / (sqrtf(sq) + EPSF);   // log2e folded into Q
    const float rk = 1.0f / (sqrtf(sk) + EPSF);

    if (cq == 0) {                                 // QP store (hi-only)
        __attribute__((aligned(16))) unsigned short qp[16];
        #pragma unroll
        for (int i = 0; i < DKK; ++i) qp[i] = f2bf(aq[i] * rq);
        const size_t base = ((size_t)bh * NN + n) * 16;
        ((uint4*)(QP + base))[0] = ((const uint4*)qp)[0];
        ((uint4*)(QP + base))[1] = ((const uint4*)qp)[1];
    } else if (cq == 1) {                          // KP store (hi-only)
        __attribute__((aligned(16))) unsigned short kp[16];
        #pragma unroll
        for (int i = 0; i < DKK; ++i) kp[i] = f2bf(ak[i] * rk);
        const size_t base = ((size_t)bh * NN + n) * 16;
        ((uint4*)(KP + base))[0] = ((const uint4*)kp)[0];
        ((uint4*)(KP + base))[1] = ((const uint4*)kp)[1];
    } else {
        // VP scatter (hi-only): cq==2 -> dv 0..7, cq==3 -> dv 8..15
        const int vslot = ((n >> 2) & 3) * 8 + ((n >> 4) & 1) * 4 + (n & 3);
        const int dv0 = (cq == 2) ? 0 : 8;
        #pragma unroll
        for (int i = 0; i < 8; ++i) {
            const int dv = dv0 + i;
            VP[(((size_t)bh * DKK + dv) * 128 + (n >> 5)) * 32 + vslot] = f2bf(av[dv]);
        }
    }
}

// ---------------------------------------------------------------------------
// One 32-key tile-pair x 4 q-frags: 12 MFMA (8 S + 4 PV), 32 exp2.
// PV packs both 16-key tiles into one MFMA (A=[V_e|V_o], B=[P_e|P_o]);
// l accumulated on the VALU (8 adds per frag) + post-loop shfl reduce.
// ---------------------------------------------------------------------------
__device__ __forceinline__ void attn_pair(
    const uint2 ke, const uint2 ko, const Frag& vc,
    const Frag* qh_, f4* oC, float* l_)
{
    const f4 zero = {0.f, 0.f, 0.f, 0.f};
    Frag kAe, kAo;
    kAe.p.lo = ke; kAe.p.hi = make_uint2(0u, 0u);
    kAo.p.lo = ko; kAo.p.hi = make_uint2(0u, 0u);

    #pragma unroll
    for (int f = 0; f < 4; ++f) {
        f4 se = __builtin_amdgcn_mfma_f32_16x16x32_bf16(kAe.v, qh_[f].v, zero, 0, 0, 0);
        f4 so = __builtin_amdgcn_mfma_f32_16x16x32_bf16(kAo.v, qh_[f].v, zero, 0, 0, 0);

        const float pe0 = __builtin_amdgcn_exp2f(se[0]);
        const float pe1 = __builtin_amdgcn_exp2f(se[1]);
        const float pe2 = __builtin_amdgcn_exp2f(se[2]);
        const float pe3 = __builtin_amdgcn_exp2f(se[3]);
        const float po0 = __builtin_amdgcn_exp2f(so[0]);
        const float po1 = __builtin_amdgcn_exp2f(so[1]);
        const float po2 = __builtin_amdgcn_exp2f(so[2]);
        const float po3 = __builtin_amdgcn_exp2f(so[3]);

        l_[f] += ((pe0 + pe1) + (pe2 + pe3)) + ((po0 + po1) + (po2 + po3));

        unsigned int u0, u1, u2, u3;
        asm("v_cvt_pk_bf16_f32 %0, %1, %2" : "=v"(u0) : "v"(pe0), "v"(pe1));
        asm("v_cvt_pk_bf16_f32 %0, %1, %2" : "=v"(u1) : "v"(pe2), "v"(pe3));
        asm("v_cvt_pk_bf16_f32 %0, %1, %2" : "=v"(u2) : "v"(po0), "v"(po1));
        asm("v_cvt_pk_bf16_f32 %0, %1, %2" : "=v"(u3) : "v"(po2), "v"(po3));
        Frag pB;
        pB.p.lo = make_uint2(u0, u1);   // even tile -> positions j0..3
        pB.p.hi = make_uint2(u2, u3);   // odd tile  -> positions j4..7

        oC[f] = __builtin_amdgcn_mfma_f32_16x16x32_bf16(vc.v, pB.v, oC[f], 0, 0, 0);
    }
}

// ---------------------------------------------------------------------------
// Stage 2 (fused): 512 blocks x 8 waves. Block = (bh, 64 q-rows); wave = one
// key split (512 keys = 16 pairs) x 4 q-frags. Per pair: 2x8B K + 1x16B V
// loads, 12 MFMA, 32 exp2. Prefetch depth 2 pairs, unroll-2, last two pairs
// peeled (no OOB read anywhere -> replay-deterministic).
// Epilogue: LDS-reduce 8 splits, normalize, write O2T.
// ---------------------------------------------------------------------------
__global__ __launch_bounds__(512, 4) void attn_kernel(
    const unsigned short* __restrict__ QP, const unsigned short* __restrict__ KP,
    const unsigned short* __restrict__ VP, float* __restrict__ O2T)
{
    const int bh    = blockIdx.x & 7;
    const int qg    = blockIdx.x >> 3;          // 0..63, 64 q-rows each
    const int split = threadIdx.x >> 6;         // 0..7
    const int lane  = threadIdx.x & 63;
    const int g = lane >> 4;
    const int r = lane & 15;

    // 4 Q frags (hi-only), each an 8B load duplicated into both B halves
    Frag qh_[4];
    #pragma unroll
    for (int f = 0; f < 4; ++f) {
        const uint2 qv = *(const uint2*)(QP + ((size_t)bh * NN + qg * 64 + f * 16 + r) * 16 + g * 4);
        qh_[f].p.lo = qv; qh_[f].p.hi = qv;
    }

    const int key0 = split * (NN / KSPLIT);
    const unsigned short* kp_p = KP + ((size_t)bh * NN + key0 + r) * 16 + g * 4;
    const unsigned short* vp_p = VP + (((size_t)bh * DKK + r) * 128 + (key0 >> 5)) * 32 + g * 8;

    f4 oC[4] = {{0.f,0.f,0.f,0.f},{0.f,0.f,0.f,0.f},{0.f,0.f,0.f,0.f},{0.f,0.f,0.f,0.f}};
    float l_[4] = {0.f, 0.f, 0.f, 0.f};

    // prefetch depth 2 pairs (pairs 0 and 1), unroll-2 main loop
    uint2 ke0 = *(const uint2*)kp_p;
    uint2 ko0 = *(const uint2*)(kp_p + 256);
    Frag  v0; v0.q = *(const uint4*)vp_p;
    uint2 ke1 = *(const uint2*)(kp_p + 512);
    uint2 ko1 = *(const uint2*)(kp_p + 768);
    Frag  v1; v1.q = *(const uint4*)(vp_p + 32);
    kp_p += 1024; vp_p += 64;                   // -> pair t+2

    for (int t = 0; t < TPAIRS - 2; t += 2) {   // 7 iters; max prefetch pair 15
        const uint2 kne0 = *(const uint2*)kp_p;
        const uint2 kno0 = *(const uint2*)(kp_p + 256);
        Frag vn0; vn0.q = *(const uint4*)vp_p;
        attn_pair(ke0, ko0, v0, qh_, oC, l_);
        const uint2 kne1 = *(const uint2*)(kp_p + 512);
        const uint2 kno1 = *(const uint2*)(kp_p + 768);
        Frag vn1; vn1.q = *(const uint4*)(vp_p + 32);
        attn_pair(ke1, ko1, v1, qh_, oC, l_);
        ke0 = kne0; ko0 = kno0; v0 = vn0;
        ke1 = kne1; ko1 = kno1; v1 = vn1;
        kp_p += 1024; vp_p += 64;
    }
    attn_pair(ke0, ko0, v0, qh_, oC, l_);       // pair 14
    attn_pair(ke1, ko1, v1, qh_, oC, l_);       // pair 15

    // per-lane l_ covers this lane's 8 key-positions per pair; reduce the
    // 4 lane-groups (stride-16 lanes) -> full split-l in every lane
    #pragma unroll
    for (int f = 0; f < 4; ++f) {
        l_[f] += __shfl_xor(l_[f], 16);
        l_[f] += __shfl_xor(l_[f], 32);
    }

    // ---- cross-split reduction in LDS ----
    __shared__ float sO[KSPLIT][4][DKK][17];    // ~34.8 KB, padded (<=2-way)
    __shared__ float sL[KSPLIT][4][17];         // ~2.2 KB
    #pragma unroll
    for (int f = 0; f < 4; ++f)
        #pragma unroll
        for (int i = 0; i < 4; ++i)
            sO[split][f][g * 4 + i][r] = oC[f][i];
    if (g == 0) {
        #pragma unroll
        for (int f = 0; f < 4; ++f) sL[split][f][r] = l_[f];
    }
    __syncthreads();

    // 512 threads: each handles (qq, dv0) and (qq, dv0+8)
    const int qq  = threadIdx.x & 63;
    const int f   = qq >> 4;
    const int rr  = qq & 15;
    const int dv0 = threadIdx.x >> 6;           // 0..7
    const int b = bh >> 2, h = bh & 3;

    float den = 0.f;
    #pragma unroll
    for (int s = 0; s < KSPLIT; ++s) den += sL[s][f][rr];
    const float rd = 1.0f / den;

    #pragma unroll
    for (int dd = 0; dd < 2; ++dd) {
        const int dv = dv0 + dd * 8;
        float num = 0.f;
        #pragma unroll
        for (int s = 0; s < KSPLIT; ++s) num += sO[s][f][dv][rr];
        O2T[((size_t)b * CC + h * DKK + dv) * NN + qg * 64 + qq] = num * rd;
    }
}

// ---------------------------------------------------------------------------
// Stage 3: y[b,c,n] = sum_{h,v} o[b,h,n,v] * wo[h,c,v] / 8.
// 4 c-outputs per thread; wo reads are block-uniform (scalar cache).
// ---------------------------------------------------------------------------
__global__ __launch_bounds__(256) void out_kernel(
    const float* __restrict__ O2T, const float* __restrict__ wo,
    float* __restrict__ y)
{
    const int idx = blockIdx.x * 256 + threadIdx.x;   // (b*16 + cg)*NN + n
    const int n   = idx & (NN - 1);
    const int bcg = idx >> 12;
    const int cg  = bcg & 15;                         // c-group of 4
    const int b   = bcg >> 4;

    const float* ob = O2T + (size_t)b * CC * NN + n;
    float acc[4] = {0.f, 0.f, 0.f, 0.f};
    #pragma unroll
    for (int h = 0; h < NHEADS; ++h)
        #pragma unroll
        for (int v = 0; v < DKK; ++v) {
            const float o = ob[(size_t)(h * DKK + v) * NN];
            #pragma unroll
            for (int c2 = 0; c2 < 4; ++c2)
                acc[c2] += o * wo[((size_t)h * CC + cg * 4 + c2) * DKK + v];
        }
    #pragma unroll
    for (int c2 = 0; c2 < 4; ++c2)
        y[((size_t)b * CC + cg * 4 + c2) * NN + n] = acc[c2] * 0.125f;
}

// ---------------------------------------------------------------------------
extern "C" void kernel_launch(void* const* d_in, const int* in_sizes, int n_in,
                              void* d_out, int out_size, void* d_ws, size_t ws_size,
                              hipStream_t stream)
{
    const float* x  = (const float*)d_in[0];
    const float* wq = (const float*)d_in[1];
    const float* wk = (const float*)d_in[2];
    const float* wv = (const float*)d_in[3];
    const float* wo = (const float*)d_in[4];
    float* y = (float*)d_out;

    const size_t QKE = (size_t)NBH * NN * 16;           // QP/KP: 512K shorts
    const size_t VE  = (size_t)NBH * DKK * 128 * 32;    // VP: 512K shorts (hi-only)
    unsigned short* QP = (unsigned short*)d_ws;
    unsigned short* KP = QP + QKE;
    unsigned short* VP = KP + QKE;
    float* O2T = (float*)(VP + VE);

    proj_kernel<<<NBH * 64, 256, 0, stream>>>(x, wq, wk, wv, QP, KP, VP);
    attn_kernel<<<NBH * 64, 512, 0, stream>>>(QP, KP, VP, O2T);
    out_kernel<<<(BB * 16 * NN) / 256, 256, 0, stream>>>(O2T, wo, y);
}